// Round 14
// baseline (746.224 us; speedup 1.0000x reference)
//
#include <hip/hip_runtime.h>
#include <hip/hip_bf16.h>
#include <math.h>
#include <stdint.h>

// ---------------------------------------------------------------------------
// SwinTransformerBlock1D.  Inputs fp32, output fp32, internal bf16 MFMA.
// B=4 L=8192 DIM=512 HEADS=8 WIN=256 HEAD_DIM=64 HID=2048.
// R19 = R18 attn/LN/vtrans + GEMMs moved to gemm128m (m97 cell):
//     R13's 256²/128KB-LDS shape locks 1 block/CU -> per-block
//     [prologue|K-loop|epilogue] strictly serial (fc1=140us, MfmaUtil 20%).
//     m97 (guide-verified 874-912 TF): 128² tile, BK=64, 4 waves, 32KB
//     single-buffer LDS, ~3 blocks/CU -> cross-BLOCK overlap hides
//     epilogue/prologue/staging (m114 mechanism).  Per tile:
//     DSR 16 frags -> lgkm0 -> barrier -> stage(t+1) 8x gld16 -> 32 MFMA
//     -> vmcnt0 -> barrier.  launch_bounds(256,3) = 3 waves/EU (VGPR cap
//     ~170; est ~150).  R14's failure was BK=32 (80cyc cover) - wrong cell.
// MFMA fragment layouts (m89/m91-verified): A[m=lane&15][k=quad*8+j],
// B[n=lane&15][k=quad*8+j]; swapped call mfma(B,A) -> lane(quad,l16) holds
// C[m=i*16+l16][n=j*16+quad*4+r] (R13-verified).
// ---------------------------------------------------------------------------

typedef __attribute__((ext_vector_type(8))) __bf16 bf16x8;
typedef __attribute__((ext_vector_type(4))) __bf16 bf16x4;
typedef __attribute__((ext_vector_type(4))) float  f32x4;

#define NTOK  32768
#define DIMC  512
#define HEADS 8
#define WIN   256
#define HD    64
#define HIDC  2048

// async global->LDS, 16B per lane; LDS dest = wave-uniform base + lane*16B
__device__ __forceinline__ void gld16(const __bf16* g, __bf16* l)
{
    __builtin_amdgcn_global_load_lds(
        (const __attribute__((address_space(1))) void*)g,
        (__attribute__((address_space(3))) void*)l, 16, 0, 0);
}

// asm ds_read_b128 at base VGPR address + literal byte offset.
#define DSR(dst, base, off) \
    asm volatile("ds_read_b128 %0, %1 offset:" off : "=v"(dst) : "v"(base))

// ---------------- 128x128 GEMM, BK=64, single-buffer, 3 blocks/CU ----------
// A (MxK row-major), Bt (NxK row-major).  256 threads = 4 waves (wr=wave>>1,
// wc=wave&1); wave computes 64x64 of C (4 m-subtiles x 4 n-subtiles).
// LDS (32KB): A slices 0..15 (slice S = msub*2+ks32: 16 rows x 32 k,
// fragment-lane order lane*8, 1KB each), B slices at +16KB.  Wave w stages
// slices S=w*4..w*4+3 of A and of B (8 gld16/thread/tile, 16 rows x 64B).
// Per tile: DSR 16 frags -> lgkm0 -> barrier (all reads done) -> stage(t+1)
// (overwrite safe) -> 32 MFMA (hides stage flight) -> vmcnt0 -> barrier.
// MODE 0: +bias; 1: +res; 2: gelu.  OUTF 1: fp32 out.
template<int MODE, int OUTF>
__global__ __launch_bounds__(256, 3) void gemm128m(
    const __bf16* __restrict__ A, int lda,
    const __bf16* __restrict__ Bt, int ldb,
    const float* __restrict__ bias,
    const void* __restrict__ res, int res_f32,
    void* __restrict__ C, int ldc, int K,
    int nM, int nN)
{
    __shared__ __bf16 lds[16384];   // A 0..8191 | B 8192..16383 (elems)
    const int tid  = threadIdx.x;
    const int wave = tid >> 6, lane = tid & 63;
    const int quad = lane >> 4, l16 = lane & 15;
    const int wr = wave >> 1, wc = wave & 1;   // 2x2 wave grid

    // XCD swizzle: id%8 = XCD; each XCD owns nM/8 consecutive m-tiles.
    const int id  = blockIdx.x;
    const int xcd = id & 7;
    const int lid = id >> 3;
    const int mq  = lid / nN;
    const int mt  = xcd * (nM >> 3) + mq;
    const int nt  = lid - mq * nN;
    const int m0 = mt * 128, n0 = nt * 128;

    // staging: wave w stages slices S = w*4+j (A and B); lane -> row
    // (S>>1)*16 + l16, k (S&1)*32 + quad*8; LDS elem S*512 + lane*8.
    int aoff[4], boff[4];
    #pragma unroll
    for (int j = 0; j < 4; j++) {
        const int S = wave * 4 + j;
        const int row = (S >> 1) * 16 + l16;
        const int kof = (S & 1) * 32 + quad * 8;
        aoff[j] = (m0 + row) * lda + kof;
        boff[j] = (n0 + row) * ldb + kof;
    }

    // ds_read bases: A frag (msub=wr*4+i, ks) at byte (wr*4+i)*2048 +
    // ks*1024 + lane*16; B at +16384 with wc.
    const uint32_t lds0 =
        (uint32_t)(uintptr_t)(__attribute__((address_space(3))) void*)&lds[0];
    const uint32_t aAd = lds0 + wr * 8192 + lane * 16;
    const uint32_t bAd = lds0 + 16384 + wc * 8192 + lane * 16;

    f32x4 acc[4][4] = {};
    bf16x8 rA[4][2], rB[4][2];

    const int ntk = K >> 6;

    // prologue: stage tile 0
    #pragma unroll
    for (int j = 0; j < 4; j++) {
        gld16(A  + aoff[j], &lds[(wave * 4 + j) * 512]);
        gld16(Bt + boff[j], &lds[8192 + (wave * 4 + j) * 512]);
    }
    asm volatile("s_waitcnt vmcnt(0)");
    __builtin_amdgcn_s_barrier();

    for (int t = 0; t < ntk; ++t) {
        // read all 16 fragments of tile t into registers
        DSR(rA[0][0], aAd, "0");    DSR(rA[0][1], aAd, "1024");
        DSR(rA[1][0], aAd, "2048"); DSR(rA[1][1], aAd, "3072");
        DSR(rA[2][0], aAd, "4096"); DSR(rA[2][1], aAd, "5120");
        DSR(rA[3][0], aAd, "6144"); DSR(rA[3][1], aAd, "7168");
        DSR(rB[0][0], bAd, "0");    DSR(rB[0][1], bAd, "1024");
        DSR(rB[1][0], bAd, "2048"); DSR(rB[1][1], bAd, "3072");
        DSR(rB[2][0], bAd, "4096"); DSR(rB[2][1], bAd, "5120");
        DSR(rB[3][0], bAd, "6144"); DSR(rB[3][1], bAd, "7168");
        asm volatile("s_waitcnt lgkmcnt(0)");
        __builtin_amdgcn_sched_barrier(0);
        __builtin_amdgcn_s_barrier();          // all waves' LDS reads done

        // stage tile t+1 (overwrites LDS; safe after barrier)
        const bool pf = (t + 1 < ntk);
        if (pf) {
            const int kn = (t + 1) << 6;
            #pragma unroll
            for (int j = 0; j < 4; j++) {
                gld16(A  + aoff[j] + kn, &lds[(wave * 4 + j) * 512]);
                gld16(Bt + boff[j] + kn, &lds[8192 + (wave * 4 + j) * 512]);
            }
        }

        // MFMA tile t (hides the stage flight)
        __builtin_amdgcn_s_setprio(1);
        #pragma unroll
        for (int i = 0; i < 4; i++)
            #pragma unroll
            for (int j = 0; j < 4; j++)
                #pragma unroll
                for (int ks = 0; ks < 2; ks++)
                    acc[i][j] = __builtin_amdgcn_mfma_f32_16x16x32_bf16(
                        rB[j][ks], rA[i][ks], acc[i][j], 0, 0, 0);
        __builtin_amdgcn_s_setprio(0);
        if (pf) asm volatile("s_waitcnt vmcnt(0)");
        __builtin_amdgcn_s_barrier();          // stage complete
    }

    // epilogue (swapped layout): lane(quad,l16) holds, for (i,j),
    // C[m0+wr*64+i*16+l16][n0+wc*64+j*16+quad*4 + r], r=0..3 consecutive.
    #pragma unroll
    for (int i = 0; i < 4; i++) {
        const int row = m0 + wr * 64 + i * 16 + l16;
        #pragma unroll
        for (int j = 0; j < 4; j++) {
            const int colb = n0 + wc * 64 + j * 16 + quad * 4;
            const size_t off = (size_t)row * ldc + colb;
            const f32x4 bv = *(const f32x4*)(bias + colb);
            f32x4 v;
            #pragma unroll
            for (int r = 0; r < 4; r++) v[r] = acc[i][j][r] + bv[r];
            if (MODE == 2) {
                #pragma unroll
                for (int r = 0; r < 4; r++)
                    v[r] = 0.5f * v[r] * (1.0f + erff(v[r] * 0.70710678118654752f));
            }
            if (MODE == 1) {
                if (res_f32) {
                    const f32x4 rv = *(const f32x4*)((const float*)res + off);
                    #pragma unroll
                    for (int r = 0; r < 4; r++) v[r] += rv[r];
                } else {
                    const bf16x4 rv = *(const bf16x4*)((const __bf16*)res + off);
                    #pragma unroll
                    for (int r = 0; r < 4; r++) v[r] += (float)rv[r];
                }
            }
            if (OUTF) {
                *(f32x4*)((float*)C + off) = v;
            } else {
                bf16x4 o;
                #pragma unroll
                for (int r = 0; r < 4; r++) o[r] = (__bf16)v[r];
                *(bf16x4*)((__bf16*)C + off) = o;
            }
        }
    }
}

// ---------------- fused attention: QK^T + bias + softmax + PV (R18) --------
__global__ __launch_bounds__(256) void attn_fused(
    const __bf16* __restrict__ qkvb, const float* __restrict__ rpb,
    const __bf16* __restrict__ Vt, __bf16* __restrict__ attnO)
{
    __shared__ __align__(16) __bf16 Ks[256 * 72];   // P overlays first 32 KB
    __shared__ float rpbs[320];
    const int bh = blockIdx.y;
    const int bw = bh >> 3, head = bh & 7;
    const int m0 = blockIdx.x * 64;
    const int tid = threadIdx.x;
    const __bf16* qb = qkvb + (size_t)bw * WIN * 1536 + head * HD;

    const int wave = tid >> 6, lane = tid & 63;
    const int quad = lane >> 4, l16 = lane & 15;

    // Q direct global->reg: wave's q-row = m0 + wave*16 + l16 (B-operand).
    bf16x8 af[2];
    #pragma unroll
    for (int ks = 0; ks < 2; ks++)
        af[ks] = *(const bf16x8*)(qb + (size_t)(m0 + wave * 16 + l16) * 1536
                                  + ks * 32 + quad * 8);

    {   // stage K (256x64), rows of 64 elems = 8 x bf16x8; and rpb slice
        const int row = tid >> 3, l8 = (tid & 7) * 8;
        #pragma unroll
        for (int p = 0; p < 8; p++) {
            const int r = p * 32 + row;
            *(bf16x8*)(Ks + r * 72 + l8) =
                *(const bf16x8*)(qb + 512 + (size_t)r * 1536 + l8);
        }
        // rpb slice: bias(i,j) = rpb[i-j+255]; i-j+255-m0 in [0,318]
        rpbs[tid] = rpb[(size_t)(m0 + tid) * HEADS + head];
        if (tid < 63) rpbs[256 + tid] = rpb[(size_t)(m0 + 256 + tid) * HEADS + head];
    }
    __syncthreads();

    // QK^T swapped: acc[nb][r] = S[q][k=nb*16+quad*4+r], q = wave*16+l16
    f32x4 acc[16];
    #pragma unroll
    for (int nb = 0; nb < 16; nb++) acc[nb] = (f32x4){0.f, 0.f, 0.f, 0.f};
    #pragma unroll
    for (int nb = 0; nb < 16; nb++) {
        #pragma unroll
        for (int ks = 0; ks < 2; ks++) {
            bf16x8 bf = *(const bf16x8*)(Ks + (nb * 16 + l16) * 72 + ks * 32 + quad * 8);
            acc[nb] = __builtin_amdgcn_mfma_f32_16x16x32_bf16(bf, af[ks], acc[nb], 0, 0, 0);
        }
    }
    // scale + bias: q = wave*16+l16 (local), k = nb*16+quad*4+r
    const int ql = wave * 16 + l16;
    #pragma unroll
    for (int nb = 0; nb < 16; nb++)
        #pragma unroll
        for (int r = 0; r < 4; r++)
            acc[nb][r] = acc[nb][r] * 0.125f
                       + rpbs[ql - (nb * 16 + quad * 4 + r) + 255];

    __syncthreads();   // all K-reads done; safe to overlay P on Ks

    // softmax for row ql (one row per lane): in-lane + cross-quad shuffles
    char* Pb = (char*)Ks;
    {
        float m = -1e30f;
        #pragma unroll
        for (int nb = 0; nb < 16; nb++)
            #pragma unroll
            for (int r = 0; r < 4; r++) m = fmaxf(m, acc[nb][r]);
        m = fmaxf(m, __shfl_xor(m, 16));
        m = fmaxf(m, __shfl_xor(m, 32));
        float s = 0.f;
        #pragma unroll
        for (int nb = 0; nb < 16; nb++)
            #pragma unroll
            for (int r = 0; r < 4; r++) {
                acc[nb][r] = __expf(acc[nb][r] - m);
                s += acc[nb][r];
            }
        s += __shfl_xor(s, 16);
        s += __shfl_xor(s, 32);
        const float inv = 1.0f / s;
        // P-write: b64 per nb at row ql, cols nb*16+quad*4..+3
        const int rx = ql & 7;
        #pragma unroll
        for (int nb = 0; nb < 16; nb++) {
            bf16x4 o;
            #pragma unroll
            for (int r = 0; r < 4; r++) o[r] = (__bf16)(acc[nb][r] * inv);
            const int c = nb * 2 + (quad >> 1);           // 16B content chunk
            *(bf16x4*)(Pb + ql * 512 + ((c ^ rx) << 4) + ((quad & 1) << 3)) = o;
        }
    }
    __syncthreads();   // P complete

    // PV: wave computes rows wave*16+l16 (A-frag m=l16), all 64 d.
    const __bf16* Vtb = Vt + (size_t)bh * (HD * WIN);
    const int prow = wave * 16 + l16;
    const int px = prow & 7;                               // == l16 & 7
    f32x4 acc2[4] = {};
    #pragma unroll
    for (int ks2 = 0; ks2 < 8; ks2++) {
        const bf16x8 pa = *(const bf16x8*)(Pb + prow * 512
                                + (((ks2 * 4 + quad) ^ px) << 4));
        #pragma unroll
        for (int nb2 = 0; nb2 < 4; nb2++) {
            const bf16x8 vf = *(const bf16x8*)(Vtb + (size_t)(nb2 * 16 + l16) * WIN
                                + ks2 * 32 + quad * 8);
            acc2[nb2] = __builtin_amdgcn_mfma_f32_16x16x32_bf16(vf, pa, acc2[nb2], 0, 0, 0);
        }
    }
    // store: out[row=m0+wave*16+l16][d=head*64+nb2*16+quad*4 + r]
    {
        const int i = m0 + wave * 16 + l16;
        __bf16* ob = attnO + (size_t)(bw * WIN + i) * DIMC + head * HD;
        #pragma unroll
        for (int nb2 = 0; nb2 < 4; nb2++) {
            bf16x4 o;
            #pragma unroll
            for (int r = 0; r < 4; r++) o[r] = (__bf16)acc2[nb2][r];
            *(bf16x4*)(ob + nb2 * 16 + quad * 4) = o;
        }
    }
}

// ---------------- V^T per (window,head): Vt[d][j] = V[j][d] ----------------
__global__ __launch_bounds__(256) void vtrans(
    const __bf16* __restrict__ qkvb, __bf16* __restrict__ Vt, int bh_base)
{
    __shared__ __align__(16) __bf16 s[WIN * 72];
    const int bh = bh_base + blockIdx.x;
    const int bw = bh >> 3, head = bh & 7;
    const int tid = threadIdx.x;
    const __bf16* V = qkvb + (size_t)bw * WIN * 1536 + 1024 + head * HD;
    #pragma unroll
    for (int it = 0; it < 8; it++) {
        int idx = it * 256 + tid;
        int j = idx >> 3;
        int d0 = (idx & 7) * 8;
        *(bf16x8*)(s + j * 72 + d0) = *(const bf16x8*)(V + (size_t)j * 1536 + d0);
    }
    __syncthreads();
    __bf16* out = Vt + (size_t)blockIdx.x * (HD * WIN);
    #pragma unroll
    for (int it = 0; it < 8; it++) {
        int idx = it * 256 + tid;
        int d  = idx >> 5;
        int j0 = (idx & 31) * 8;
        bf16x8 v;
        #pragma unroll
        for (int j = 0; j < 8; j++) v[j] = s[(j0 + j) * 72 + d];
        *(bf16x8*)(out + (size_t)d * WIN + j0) = v;
    }
}

// ---------------- LayerNorm: one wave per token ----------------------------
__global__ __launch_bounds__(256) void ln_kernel(
    const void* X, int xf,
    const float* __restrict__ g, const float* __restrict__ b,
    __bf16* O)
{
    const int tok  = blockIdx.x * 4 + (threadIdx.x >> 6);
    const int lane = threadIdx.x & 63;
    const size_t base = (size_t)tok * DIMC + lane * 8;
    float v[8];
    if (xf) {
        const float* xp = (const float*)X + base;
        f32x4 a = *(const f32x4*)xp;
        f32x4 c = *(const f32x4*)(xp + 4);
        #pragma unroll
        for (int j = 0; j < 4; j++) { v[j] = a[j]; v[4 + j] = c[j]; }
    } else {
        bf16x8 xv = *(const bf16x8*)((const __bf16*)X + base);
        #pragma unroll
        for (int j = 0; j < 8; j++) v[j] = (float)xv[j];
    }
    float s = 0.f, s2 = 0.f;
    #pragma unroll
    for (int j = 0; j < 8; j++) { s += v[j]; s2 += v[j] * v[j]; }
    #pragma unroll
    for (int off = 32; off; off >>= 1) { s += __shfl_xor(s, off); s2 += __shfl_xor(s2, off); }
    const float mean = s * (1.0f / DIMC);
    const float var  = s2 * (1.0f / DIMC) - mean * mean;
    const float rstd = rsqrtf(var + 1e-5f);
    f32x4 ga = *(const f32x4*)(g + lane * 8);
    f32x4 gc = *(const f32x4*)(g + lane * 8 + 4);
    f32x4 ba = *(const f32x4*)(b + lane * 8);
    f32x4 bc = *(const f32x4*)(b + lane * 8 + 4);
    bf16x8 ov;
    #pragma unroll
    for (int j = 0; j < 4; j++) {
        ov[j]     = (__bf16)((v[j]     - mean) * rstd * ga[j] + ba[j]);
        ov[4 + j] = (__bf16)((v[4 + j] - mean) * rstd * gc[j] + bc[j]);
    }
    *(bf16x8*)(O + base) = ov;
}

// ---------------- weight transpose+cast: fp32 KxN -> bf16 NxK --------------
__global__ __launch_bounds__(256) void wtrans(
    const float* __restrict__ W, __bf16* __restrict__ Wt, int K, int N)
{
    __shared__ __align__(16) __bf16 s[64 * 72];
    const int kb = blockIdx.y * 64, nb = blockIdx.x * 64;
    const int tid = threadIdx.x;
    #pragma unroll
    for (int it = 0; it < 2; it++) {
        int idx = it * 256 + tid;
        int lk = idx >> 3;
        int ln = (idx & 7) * 8;
        const float* wp = W + (size_t)(kb + lk) * N + nb + ln;
        f32x4 a = *(const f32x4*)wp;
        f32x4 c = *(const f32x4*)(wp + 4);
        bf16x8 v;
        #pragma unroll
        for (int j = 0; j < 4; j++) { v[j] = (__bf16)a[j]; v[4 + j] = (__bf16)c[j]; }
        *(bf16x8*)(s + lk * 72 + ln) = v;
    }
    __syncthreads();
    #pragma unroll
    for (int it = 0; it < 2; it++) {
        int idx = it * 256 + tid;
        int ln  = idx >> 3;
        int lkv = (idx & 7) * 8;
        bf16x8 v;
        #pragma unroll
        for (int j = 0; j < 8; j++) v[j] = s[(lkv + j) * 72 + ln];
        *(bf16x8*)(Wt + (size_t)(nb + ln) * K + kb + lkv) = v;
    }
}

// ---------------------------------------------------------------------------
extern "C" void kernel_launch(void* const* d_in, const int* in_sizes, int n_in,
                              void* d_out, int out_size, void* d_ws, size_t ws_size,
                              hipStream_t stream)
{
    const float* x      = (const float*)d_in[0];
    const float* n1g    = (const float*)d_in[1];
    const float* n1b    = (const float*)d_in[2];
    const float* qkv_w  = (const float*)d_in[3];
    const float* qkv_b  = (const float*)d_in[4];
    const float* rpb    = (const float*)d_in[5];
    const float* proj_w = (const float*)d_in[6];
    const float* proj_b = (const float*)d_in[7];
    const float* n2g    = (const float*)d_in[8];
    const float* n2b    = (const float*)d_in[9];
    const float* fc1_w  = (const float*)d_in[10];
    const float* fc1_b  = (const float*)d_in[11];
    const float* fc2_w  = (const float*)d_in[12];
    const float* fc2_b  = (const float*)d_in[13];
    float* out = (float*)d_out;

    // workspace layout (bytes); slots reused sequentially
    char* ws = (char*)d_ws;
    __bf16* qkvb  = (__bf16*)(ws + 0);           // 96 MB (dead after attn)
    __bf16* hid   = (__bf16*)(ws + 0);           // 128 MB (steps 7-8)
    __bf16* Vt    = (__bf16*)(ws + 100663296);   // 96..128 MB (dead after attn)
    __bf16* h     = (__bf16*)(ws + 134217728);   // LN1 out; later y/x2
    __bf16* y     = h;
    __bf16* attnO = (__bf16*)(ws + 167772160);
    __bf16* wq_t  = (__bf16*)(ws + 209715200);   // 1536x512
    __bf16* wp_t  = (__bf16*)(ws + 211288064);   // 512x512
    __bf16* w1_t  = (__bf16*)(ws + 211812352);   // 2048x512
    __bf16* w2_t  = (__bf16*)(ws + 213909504);   // 512x2048

    // 1) weight transposes (tiny)
    wtrans<<<dim3(1536 / 64, 512 / 64),  256, 0, stream>>>(qkv_w, wq_t, 512, 1536);
    wtrans<<<dim3(512 / 64,  512 / 64),  256, 0, stream>>>(proj_w, wp_t, 512, 512);
    wtrans<<<dim3(2048 / 64, 512 / 64),  256, 0, stream>>>(fc1_w, w1_t, 512, 2048);
    wtrans<<<dim3(512 / 64,  2048 / 64), 256, 0, stream>>>(fc2_w, w2_t, 2048, 512);

    // 2) LN1: h = LN(x)
    ln_kernel<<<NTOK / 4, 256, 0, stream>>>(x, 1, n1g, n1b, h);

    // 3) qkv = h @ qkv_w + qkv_b   (M=32768, N=1536, K=512); nM=256 nN=12
    gemm128m<0, 0><<<3072, 256, 0, stream>>>(
        h, DIMC, wq_t, DIMC, qkv_b, nullptr, 0, qkvb, 1536, DIMC, 256, 12);

    // 4) attention: V^T then fused QK^T+softmax+PV over all 1024 (bw,head)
    vtrans<<<1024, 256, 0, stream>>>(qkvb, Vt, 0);
    attn_fused<<<dim3(4, 1024), 256, 0, stream>>>(qkvb, rpb, Vt, attnO);

    // 5) y = x + attnO @ proj_w + proj_b   (N=512, K=512); nM=256 nN=4
    gemm128m<1, 0><<<1024, 256, 0, stream>>>(
        attnO, DIMC, wp_t, DIMC, proj_b, x, 1, y, DIMC, DIMC, 256, 4);

    // 6) LN2 in place: x2 = LN(y)
    ln_kernel<<<NTOK / 4, 256, 0, stream>>>(y, 0, n2g, n2b, y);

    // 7) hid = gelu(x2 @ fc1_w + fc1_b)   (N=2048, K=512); nM=256 nN=16
    gemm128m<2, 0><<<4096, 256, 0, stream>>>(
        y, DIMC, w1_t, DIMC, fc1_b, nullptr, 0, hid, HIDC, DIMC, 256, 16);

    // 8) out(fp32) = x2 + hid @ fc2_w + fc2_b  (N=512, K=2048); nM=256 nN=4
    gemm128m<1, 1><<<1024, 256, 0, stream>>>(
        hid, HIDC, w2_t, HIDC, fc2_b, y, 0, out, DIMC, HIDC, 256, 4);
}

// Round 15
// 687.985 us; speedup vs baseline: 1.0847x; 1.0847x over previous
//
#include <hip/hip_runtime.h>
#include <hip/hip_bf16.h>
#include <math.h>
#include <stdint.h>

// ---------------------------------------------------------------------------
// SwinTransformerBlock1D.  Inputs fp32, output fp32, internal bf16 MFMA.
// B=4 L=8192 DIM=512 HEADS=8 WIN=256 HEAD_DIM=64 HID=2048.
// R20 = R18 exact revert (verified 633.96us; session best).
//     R19 post-mortem: "m97 cell" transplant was NOT m97 -- single-buffer
//     loop forces vmcnt(0)+2 barriers per tile with only 32 MFMA (~160cyc)
//     cover vs ~900cyc staging flight; 2.4 blocks/CU can't absorb a stall
//     every block pays every tile (fc1 140->162).  Verified local optimum
//     for K=512 shapes: R13-gemm256 (1 block/CU, 4-phase, counted vmcnt,
//     ~500 TF).  Escapes tried & failed: deeper pipeline (R16, reg cliff),
//     thin-tile multiblock (R14), single-buffer multiblock (R19).
// Content: R13 gemm256 (4-phase 2-tile counted-vmcnt pipeline, swapped-
//     operand MFMA + vectorized epilogue) + R18 attention (swapped QK^T,
//     one q-row/lane softmax, Q global->reg, no Qs LDS -> 38.2KB,
//     P->LDS swizzled overlay, PV vs global Vt, bf16x4 stores).
// MFMA fragment layouts (m89/m91-verified): A[m=lane&15][k=quad*8+j],
// B[n=lane&15][k=quad*8+j]; mfma(X,Y) -> lane(quad,l16) holds
// D[m(X-row)=quad*4+r][n(Y-row)=l16]  (R13-verified swapped mapping).
// ---------------------------------------------------------------------------

typedef __attribute__((ext_vector_type(8))) __bf16 bf16x8;
typedef __attribute__((ext_vector_type(4))) __bf16 bf16x4;
typedef __attribute__((ext_vector_type(4))) float  f32x4;

#define NTOK  32768
#define DIMC  512
#define HEADS 8
#define WIN   256
#define HD    64
#define HIDC  2048

// async global->LDS, 16B per lane; LDS dest = wave-uniform base + lane*16B
__device__ __forceinline__ void gld16(const __bf16* g, __bf16* l)
{
    __builtin_amdgcn_global_load_lds(
        (const __attribute__((address_space(1))) void*)g,
        (__attribute__((address_space(3))) void*)l, 16, 0, 0);
}

// asm ds_read_b128 at base VGPR address + literal byte offset.
#define DSR(dst, base, off) \
    asm volatile("ds_read_b128 %0, %1 offset:" off : "=v"(dst) : "v"(base))

// ---------------- 256x256 GEMM, 4-phase, 2-tile-deep pipeline (R13) --------
template<int MODE, int OUTF>
__global__ __launch_bounds__(512, 2) void gemm256(
    const __bf16* __restrict__ A, int lda,
    const __bf16* __restrict__ Bt, int ldb,
    const float* __restrict__ bias,
    const void* __restrict__ res, int res_f32,
    void* __restrict__ C, int ldc, int K,
    int nM, int nN)
{
    __shared__ __bf16 lds[2][2][16384];   // [buf][A=0/B=1][slice*512 + lane*8]
    const int tid  = threadIdx.x;
    const int wave = tid >> 6, lane = tid & 63;
    const int quad = lane >> 4, l16 = lane & 15;
    const int wm = wave >> 2, wn = wave & 3;   // 2x4 wave grid

    // XCD swizzle: id%8 = XCD; each XCD owns nM/8 consecutive m-tiles.
    const int id  = blockIdx.x;
    const int xcd = id & 7;
    const int lid = id >> 3;
    const int mq  = lid / nN;
    const int mt  = xcd * (nM >> 3) + mq;
    const int nt  = lid - mq * nN;
    const int m0 = mt * 256, n0 = nt * 256;

    int aoff[4], boff[4];
    #pragma unroll
    for (int j = 0; j < 4; j++) {
        const int S = wave * 4 + j;
        const int row = (S >> 1) * 16 + l16;
        const int kof = (S & 1) * 32 + quad * 8;
        aoff[j] = (m0 + row) * lda + kof;
        boff[j] = (n0 + row) * ldb + kof;
    }

    const uint32_t lds0 =
        (uint32_t)(uintptr_t)(__attribute__((address_space(3))) void*)&lds[0][0][0];
    const uint32_t aAd0 = lds0 + wm * 16384 + lane * 16;
    const uint32_t bAd0 = lds0 + 32768 + wn * 8192 + lane * 16;

    f32x4 acc[8][4] = {};
    bf16x8 rA[4][2], rB[4][2];

    const int ntk = K >> 6;

    #pragma unroll
    for (int j = 0; j < 4; j++) {
        gld16(A  + aoff[j], &lds[0][0][(wave * 4 + j) * 512]);
        gld16(Bt + boff[j], &lds[0][1][(wave * 4 + j) * 512]);
    }
    #pragma unroll
    for (int j = 0; j < 4; j++) {
        gld16(A  + aoff[j] + 64, &lds[1][0][(wave * 4 + j) * 512]);
        gld16(Bt + boff[j] + 64, &lds[1][1][(wave * 4 + j) * 512]);
    }
    asm volatile("s_waitcnt vmcnt(8)");
    __builtin_amdgcn_s_barrier();

    for (int t = 0; t < ntk; ++t) {
        const int buf = t & 1;
        const uint32_t aAd = aAd0 + buf * 65536;
        const uint32_t bAd = bAd0 + buf * 65536;
        const bool pf = (t + 2 < ntk);
        const int kn = (t + 2) << 6;

        // ---- phase 0: ds_read A m0-3 + B n0-1; mfma m0-3 x n0-1
        DSR(rA[0][0], aAd, "0");    DSR(rA[0][1], aAd, "1024");
        DSR(rA[1][0], aAd, "2048"); DSR(rA[1][1], aAd, "3072");
        DSR(rA[2][0], aAd, "4096"); DSR(rA[2][1], aAd, "5120");
        DSR(rA[3][0], aAd, "6144"); DSR(rA[3][1], aAd, "7168");
        DSR(rB[0][0], bAd, "0");    DSR(rB[0][1], bAd, "1024");
        DSR(rB[1][0], bAd, "2048"); DSR(rB[1][1], bAd, "3072");
        __builtin_amdgcn_s_barrier();
        asm volatile("s_waitcnt lgkmcnt(0)");
        __builtin_amdgcn_sched_barrier(0);
        __builtin_amdgcn_s_setprio(1);
        #pragma unroll
        for (int i = 0; i < 4; i++)
            #pragma unroll
            for (int j = 0; j < 2; j++)
                #pragma unroll
                for (int ks = 0; ks < 2; ks++)
                    acc[i][j] = __builtin_amdgcn_mfma_f32_16x16x32_bf16(
                        rB[j][ks], rA[i][ks], acc[i][j], 0, 0, 0);
        __builtin_amdgcn_s_setprio(0);
        __builtin_amdgcn_s_barrier();

        // ---- phase 1: ds_read B n2-3; mfma m0-3 x n2-3
        DSR(rB[2][0], bAd, "4096"); DSR(rB[2][1], bAd, "5120");
        DSR(rB[3][0], bAd, "6144"); DSR(rB[3][1], bAd, "7168");
        __builtin_amdgcn_s_barrier();
        asm volatile("s_waitcnt lgkmcnt(0)");
        __builtin_amdgcn_sched_barrier(0);
        __builtin_amdgcn_s_setprio(1);
        #pragma unroll
        for (int i = 0; i < 4; i++)
            #pragma unroll
            for (int j = 2; j < 4; j++)
                #pragma unroll
                for (int ks = 0; ks < 2; ks++)
                    acc[i][j] = __builtin_amdgcn_mfma_f32_16x16x32_bf16(
                        rB[j][ks], rA[i][ks], acc[i][j], 0, 0, 0);
        __builtin_amdgcn_s_setprio(0);
        __builtin_amdgcn_s_barrier();

        // ---- phase 2: ds_read A m4-7; stage B(t+2)
        DSR(rA[0][0], aAd, "8192");  DSR(rA[0][1], aAd, "9216");
        DSR(rA[1][0], aAd, "10240"); DSR(rA[1][1], aAd, "11264");
        DSR(rA[2][0], aAd, "12288"); DSR(rA[2][1], aAd, "13312");
        DSR(rA[3][0], aAd, "14336"); DSR(rA[3][1], aAd, "15360");
        if (pf) {
            #pragma unroll
            for (int j = 0; j < 4; j++)
                gld16(Bt + boff[j] + kn, &lds[buf][1][(wave * 4 + j) * 512]);
        }
        __builtin_amdgcn_s_barrier();
        asm volatile("s_waitcnt lgkmcnt(0)");
        __builtin_amdgcn_sched_barrier(0);
        __builtin_amdgcn_s_setprio(1);
        #pragma unroll
        for (int i = 0; i < 4; i++)
            #pragma unroll
            for (int j = 0; j < 2; j++)
                #pragma unroll
                for (int ks = 0; ks < 2; ks++)
                    acc[4 + i][j] = __builtin_amdgcn_mfma_f32_16x16x32_bf16(
                        rB[j][ks], rA[i][ks], acc[4 + i][j], 0, 0, 0);
        __builtin_amdgcn_s_setprio(0);
        __builtin_amdgcn_s_barrier();

        // ---- phase 3: stage A(t+2); mfma m4-7 x n2-3; counted boundary wait
        if (pf) {
            #pragma unroll
            for (int j = 0; j < 4; j++)
                gld16(A + aoff[j] + kn, &lds[buf][0][(wave * 4 + j) * 512]);
        }
        __builtin_amdgcn_s_setprio(1);
        #pragma unroll
        for (int i = 0; i < 4; i++)
            #pragma unroll
            for (int j = 2; j < 4; j++)
                #pragma unroll
                for (int ks = 0; ks < 2; ks++)
                    acc[4 + i][j] = __builtin_amdgcn_mfma_f32_16x16x32_bf16(
                        rB[j][ks], rA[i][ks], acc[4 + i][j], 0, 0, 0);
        __builtin_amdgcn_s_setprio(0);
        if (pf)                  asm volatile("s_waitcnt vmcnt(8)");
        else if (t + 1 < ntk)    asm volatile("s_waitcnt vmcnt(0)");
        __builtin_amdgcn_s_barrier();
    }

    // epilogue (swapped layout): lane(quad,l16) holds, for (i,j),
    // C[m0+wm*128+i*16+l16][n0+wn*64+j*16+quad*4 + r], r=0..3 consecutive.
    #pragma unroll
    for (int i = 0; i < 8; i++) {
        const int row = m0 + wm * 128 + i * 16 + l16;
        #pragma unroll
        for (int j = 0; j < 4; j++) {
            const int colb = n0 + wn * 64 + j * 16 + quad * 4;
            const size_t off = (size_t)row * ldc + colb;
            const f32x4 bv = *(const f32x4*)(bias + colb);
            f32x4 v;
            #pragma unroll
            for (int r = 0; r < 4; r++) v[r] = acc[i][j][r] + bv[r];
            if (MODE == 2) {
                #pragma unroll
                for (int r = 0; r < 4; r++)
                    v[r] = 0.5f * v[r] * (1.0f + erff(v[r] * 0.70710678118654752f));
            }
            if (MODE == 1) {
                if (res_f32) {
                    const f32x4 rv = *(const f32x4*)((const float*)res + off);
                    #pragma unroll
                    for (int r = 0; r < 4; r++) v[r] += rv[r];
                } else {
                    const bf16x4 rv = *(const bf16x4*)((const __bf16*)res + off);
                    #pragma unroll
                    for (int r = 0; r < 4; r++) v[r] += (float)rv[r];
                }
            }
            if (OUTF) {
                *(f32x4*)((float*)C + off) = v;
            } else {
                bf16x4 o;
                #pragma unroll
                for (int r = 0; r < 4; r++) o[r] = (__bf16)v[r];
                *(bf16x4*)((__bf16*)C + off) = o;
            }
        }
    }
}

// ---------------- fused attention: QK^T + bias + softmax + PV (R18) --------
// One block: 64 q-rows x full 256 k for one (window,head).  4 waves.
// QK phase (swapped): mfma(K_frag, Q_frag) -> lane(quad,l16) holds
// S[q = wave*16+l16][k = nb*16+quad*4+r] -- one q-row per lane.  Q loaded
// global->reg (no Qs LDS); K staged in LDS (shared by all waves).
// Softmax: in-lane reduce over 64 vals + shfl_xor(16,32) across quads;
// P-writes 16x b64 per lane into swizzled P overlay on Ks (chunk
// c=nb*2+(quad>>1) at slot c^(row&7), half (quad&1)).  PV phase: wave owns
// rows wave*16+l16 as A-frag m=l16; V^T frags read from global Vt (LLC);
// swapped mfma(vf, pa) -> lane holds out[row=wave*16+l16][d=nb2*16+quad*4+r]
// -> bf16x4 stores.
__global__ __launch_bounds__(256) void attn_fused(
    const __bf16* __restrict__ qkvb, const float* __restrict__ rpb,
    const __bf16* __restrict__ Vt, __bf16* __restrict__ attnO)
{
    __shared__ __align__(16) __bf16 Ks[256 * 72];   // P overlays first 32 KB
    __shared__ float rpbs[320];
    const int bh = blockIdx.y;
    const int bw = bh >> 3, head = bh & 7;
    const int m0 = blockIdx.x * 64;
    const int tid = threadIdx.x;
    const __bf16* qb = qkvb + (size_t)bw * WIN * 1536 + head * HD;

    const int wave = tid >> 6, lane = tid & 63;
    const int quad = lane >> 4, l16 = lane & 15;

    // Q direct global->reg: wave's q-row = m0 + wave*16 + l16 (B-operand).
    bf16x8 af[2];
    #pragma unroll
    for (int ks = 0; ks < 2; ks++)
        af[ks] = *(const bf16x8*)(qb + (size_t)(m0 + wave * 16 + l16) * 1536
                                  + ks * 32 + quad * 8);

    {   // stage K (256x64), rows of 64 elems = 8 x bf16x8; and rpb slice
        const int row = tid >> 3, l8 = (tid & 7) * 8;
        #pragma unroll
        for (int p = 0; p < 8; p++) {
            const int r = p * 32 + row;
            *(bf16x8*)(Ks + r * 72 + l8) =
                *(const bf16x8*)(qb + 512 + (size_t)r * 1536 + l8);
        }
        // rpb slice: bias(i,j) = rpb[i-j+255]; i-j+255-m0 in [0,318]
        rpbs[tid] = rpb[(size_t)(m0 + tid) * HEADS + head];
        if (tid < 63) rpbs[256 + tid] = rpb[(size_t)(m0 + 256 + tid) * HEADS + head];
    }
    __syncthreads();

    // QK^T swapped: acc[nb][r] = S[q][k=nb*16+quad*4+r], q = wave*16+l16
    f32x4 acc[16];
    #pragma unroll
    for (int nb = 0; nb < 16; nb++) acc[nb] = (f32x4){0.f, 0.f, 0.f, 0.f};
    #pragma unroll
    for (int nb = 0; nb < 16; nb++) {
        #pragma unroll
        for (int ks = 0; ks < 2; ks++) {
            bf16x8 bf = *(const bf16x8*)(Ks + (nb * 16 + l16) * 72 + ks * 32 + quad * 8);
            acc[nb] = __builtin_amdgcn_mfma_f32_16x16x32_bf16(bf, af[ks], acc[nb], 0, 0, 0);
        }
    }
    // scale + bias: q = wave*16+l16 (local), k = nb*16+quad*4+r
    const int ql = wave * 16 + l16;
    #pragma unroll
    for (int nb = 0; nb < 16; nb++)
        #pragma unroll
        for (int r = 0; r < 4; r++)
            acc[nb][r] = acc[nb][r] * 0.125f
                       + rpbs[ql - (nb * 16 + quad * 4 + r) + 255];

    __syncthreads();   // all K-reads done; safe to overlay P on Ks

    // softmax for row ql (one row per lane): in-lane + cross-quad shuffles
    char* Pb = (char*)Ks;
    {
        float m = -1e30f;
        #pragma unroll
        for (int nb = 0; nb < 16; nb++)
            #pragma unroll
            for (int r = 0; r < 4; r++) m = fmaxf(m, acc[nb][r]);
        m = fmaxf(m, __shfl_xor(m, 16));
        m = fmaxf(m, __shfl_xor(m, 32));
        float s = 0.f;
        #pragma unroll
        for (int nb = 0; nb < 16; nb++)
            #pragma unroll
            for (int r = 0; r < 4; r++) {
                acc[nb][r] = __expf(acc[nb][r] - m);
                s += acc[nb][r];
            }
        s += __shfl_xor(s, 16);
        s += __shfl_xor(s, 32);
        const float inv = 1.0f / s;
        // P-write: b64 per nb at row ql, cols nb*16+quad*4..+3
        const int rx = ql & 7;
        #pragma unroll
        for (int nb = 0; nb < 16; nb++) {
            bf16x4 o;
            #pragma unroll
            for (int r = 0; r < 4; r++) o[r] = (__bf16)(acc[nb][r] * inv);
            const int c = nb * 2 + (quad >> 1);           // 16B content chunk
            *(bf16x4*)(Pb + ql * 512 + ((c ^ rx) << 4) + ((quad & 1) << 3)) = o;
        }
    }
    __syncthreads();   // P complete

    // PV: wave computes rows wave*16+l16 (A-frag m=l16), all 64 d.
    const __bf16* Vtb = Vt + (size_t)bh * (HD * WIN);
    const int prow = wave * 16 + l16;
    const int px = prow & 7;                               // == l16 & 7
    f32x4 acc2[4] = {};
    #pragma unroll
    for (int ks2 = 0; ks2 < 8; ks2++) {
        const bf16x8 pa = *(const bf16x8*)(Pb + prow * 512
                                + (((ks2 * 4 + quad) ^ px) << 4));
        #pragma unroll
        for (int nb2 = 0; nb2 < 4; nb2++) {
            const bf16x8 vf = *(const bf16x8*)(Vtb + (size_t)(nb2 * 16 + l16) * WIN
                                + ks2 * 32 + quad * 8);
            acc2[nb2] = __builtin_amdgcn_mfma_f32_16x16x32_bf16(vf, pa, acc2[nb2], 0, 0, 0);
        }
    }
    // store: out[row=m0+wave*16+l16][d=head*64+nb2*16+quad*4 + r]
    {
        const int i = m0 + wave * 16 + l16;
        __bf16* ob = attnO + (size_t)(bw * WIN + i) * DIMC + head * HD;
        #pragma unroll
        for (int nb2 = 0; nb2 < 4; nb2++) {
            bf16x4 o;
            #pragma unroll
            for (int r = 0; r < 4; r++) o[r] = (__bf16)acc2[nb2][r];
            *(bf16x4*)(ob + nb2 * 16 + quad * 4) = o;
        }
    }
}

// ---------------- V^T per (window,head): Vt[d][j] = V[j][d] ----------------
__global__ __launch_bounds__(256) void vtrans(
    const __bf16* __restrict__ qkvb, __bf16* __restrict__ Vt, int bh_base)
{
    __shared__ __align__(16) __bf16 s[WIN * 72];
    const int bh = bh_base + blockIdx.x;
    const int bw = bh >> 3, head = bh & 7;
    const int tid = threadIdx.x;
    const __bf16* V = qkvb + (size_t)bw * WIN * 1536 + 1024 + head * HD;
    #pragma unroll
    for (int it = 0; it < 8; it++) {
        int idx = it * 256 + tid;
        int j = idx >> 3;
        int d0 = (idx & 7) * 8;
        *(bf16x8*)(s + j * 72 + d0) = *(const bf16x8*)(V + (size_t)j * 1536 + d0);
    }
    __syncthreads();
    __bf16* out = Vt + (size_t)blockIdx.x * (HD * WIN);
    #pragma unroll
    for (int it = 0; it < 8; it++) {
        int idx = it * 256 + tid;
        int d  = idx >> 5;
        int j0 = (idx & 31) * 8;
        bf16x8 v;
        #pragma unroll
        for (int j = 0; j < 8; j++) v[j] = s[(j0 + j) * 72 + d];
        *(bf16x8*)(out + (size_t)d * WIN + j0) = v;
    }
}

// ---------------- LayerNorm: one wave per token ----------------------------
__global__ __launch_bounds__(256) void ln_kernel(
    const void* X, int xf,
    const float* __restrict__ g, const float* __restrict__ b,
    __bf16* O)
{
    const int tok  = blockIdx.x * 4 + (threadIdx.x >> 6);
    const int lane = threadIdx.x & 63;
    const size_t base = (size_t)tok * DIMC + lane * 8;
    float v[8];
    if (xf) {
        const float* xp = (const float*)X + base;
        f32x4 a = *(const f32x4*)xp;
        f32x4 c = *(const f32x4*)(xp + 4);
        #pragma unroll
        for (int j = 0; j < 4; j++) { v[j] = a[j]; v[4 + j] = c[j]; }
    } else {
        bf16x8 xv = *(const bf16x8*)((const __bf16*)X + base);
        #pragma unroll
        for (int j = 0; j < 8; j++) v[j] = (float)xv[j];
    }
    float s = 0.f, s2 = 0.f;
    #pragma unroll
    for (int j = 0; j < 8; j++) { s += v[j]; s2 += v[j] * v[j]; }
    #pragma unroll
    for (int off = 32; off; off >>= 1) { s += __shfl_xor(s, off); s2 += __shfl_xor(s2, off); }
    const float mean = s * (1.0f / DIMC);
    const float var  = s2 * (1.0f / DIMC) - mean * mean;
    const float rstd = rsqrtf(var + 1e-5f);
    f32x4 ga = *(const f32x4*)(g + lane * 8);
    f32x4 gc = *(const f32x4*)(g + lane * 8 + 4);
    f32x4 ba = *(const f32x4*)(b + lane * 8);
    f32x4 bc = *(const f32x4*)(b + lane * 8 + 4);
    bf16x8 ov;
    #pragma unroll
    for (int j = 0; j < 4; j++) {
        ov[j]     = (__bf16)((v[j]     - mean) * rstd * ga[j] + ba[j]);
        ov[4 + j] = (__bf16)((v[4 + j] - mean) * rstd * gc[j] + bc[j]);
    }
    *(bf16x8*)(O + base) = ov;
}

// ---------------- weight transpose+cast: fp32 KxN -> bf16 NxK --------------
__global__ __launch_bounds__(256) void wtrans(
    const float* __restrict__ W, __bf16* __restrict__ Wt, int K, int N)
{
    __shared__ __align__(16) __bf16 s[64 * 72];
    const int kb = blockIdx.y * 64, nb = blockIdx.x * 64;
    const int tid = threadIdx.x;
    #pragma unroll
    for (int it = 0; it < 2; it++) {
        int idx = it * 256 + tid;
        int lk = idx >> 3;
        int ln = (idx & 7) * 8;
        const float* wp = W + (size_t)(kb + lk) * N + nb + ln;
        f32x4 a = *(const f32x4*)wp;
        f32x4 c = *(const f32x4*)(wp + 4);
        bf16x8 v;
        #pragma unroll
        for (int j = 0; j < 4; j++) { v[j] = (__bf16)a[j]; v[4 + j] = (__bf16)c[j]; }
        *(bf16x8*)(s + lk * 72 + ln) = v;
    }
    __syncthreads();
    #pragma unroll
    for (int it = 0; it < 2; it++) {
        int idx = it * 256 + tid;
        int ln  = idx >> 3;
        int lkv = (idx & 7) * 8;
        bf16x8 v;
        #pragma unroll
        for (int j = 0; j < 8; j++) v[j] = s[(lkv + j) * 72 + ln];
        *(bf16x8*)(Wt + (size_t)(nb + ln) * K + kb + lkv) = v;
    }
}

// ---------------------------------------------------------------------------
extern "C" void kernel_launch(void* const* d_in, const int* in_sizes, int n_in,
                              void* d_out, int out_size, void* d_ws, size_t ws_size,
                              hipStream_t stream)
{
    const float* x      = (const float*)d_in[0];
    const float* n1g    = (const float*)d_in[1];
    const float* n1b    = (const float*)d_in[2];
    const float* qkv_w  = (const float*)d_in[3];
    const float* qkv_b  = (const float*)d_in[4];
    const float* rpb    = (const float*)d_in[5];
    const float* proj_w = (const float*)d_in[6];
    const float* proj_b = (const float*)d_in[7];
    const float* n2g    = (const float*)d_in[8];
    const float* n2b    = (const float*)d_in[9];
    const float* fc1_w  = (const float*)d_in[10];
    const float* fc1_b  = (const float*)d_in[11];
    const float* fc2_w  = (const float*)d_in[12];
    const float* fc2_b  = (const float*)d_in[13];
    float* out = (float*)d_out;

    // workspace layout (bytes); slots reused sequentially
    char* ws = (char*)d_ws;
    __bf16* qkvb  = (__bf16*)(ws + 0);           // 96 MB (dead after attn)
    __bf16* hid   = (__bf16*)(ws + 0);           // 128 MB (steps 7-8)
    __bf16* Vt    = (__bf16*)(ws + 100663296);   // 96..128 MB (dead after attn)
    __bf16* h     = (__bf16*)(ws + 134217728);   // LN1 out; later y/x2
    __bf16* y     = h;
    __bf16* attnO = (__bf16*)(ws + 167772160);
    __bf16* wq_t  = (__bf16*)(ws + 209715200);   // 1536x512
    __bf16* wp_t  = (__bf16*)(ws + 211288064);   // 512x512
    __bf16* w1_t  = (__bf16*)(ws + 211812352);   // 2048x512
    __bf16* w2_t  = (__bf16*)(ws + 213909504);   // 512x2048

    // 1) weight transposes (tiny)
    wtrans<<<dim3(1536 / 64, 512 / 64),  256, 0, stream>>>(qkv_w, wq_t, 512, 1536);
    wtrans<<<dim3(512 / 64,  512 / 64),  256, 0, stream>>>(proj_w, wp_t, 512, 512);
    wtrans<<<dim3(2048 / 64, 512 / 64),  256, 0, stream>>>(fc1_w, w1_t, 512, 2048);
    wtrans<<<dim3(512 / 64,  2048 / 64), 256, 0, stream>>>(fc2_w, w2_t, 2048, 512);

    // 2) LN1: h = LN(x)
    ln_kernel<<<NTOK / 4, 256, 0, stream>>>(x, 1, n1g, n1b, h);

    // 3) qkv = h @ qkv_w + qkv_b   (M=32768, N=1536, K=512); nM=128 nN=6
    gemm256<0, 0><<<768, 512, 0, stream>>>(
        h, DIMC, wq_t, DIMC, qkv_b, nullptr, 0, qkvb, 1536, DIMC, 128, 6);

    // 4) attention: V^T then fused QK^T+softmax+PV over all 1024 (bw,head)
    vtrans<<<1024, 256, 0, stream>>>(qkvb, Vt, 0);
    attn_fused<<<dim3(4, 1024), 256, 0, stream>>>(qkvb, rpb, Vt, attnO);

    // 5) y = x + attnO @ proj_w + proj_b   (N=512, K=512); nM=128 nN=2
    gemm256<1, 0><<<256, 512, 0, stream>>>(
        attnO, DIMC, wp_t, DIMC, proj_b, x, 1, y, DIMC, DIMC, 128, 2);

    // 6) LN2 in place: x2 = LN(y)
    ln_kernel<<<NTOK / 4, 256, 0, stream>>>(y, 0, n2g, n2b, y);

    // 7) hid = gelu(x2 @ fc1_w + fc1_b)   (N=2048, K=512); nM=128 nN=8
    gemm256<2, 0><<<1024, 512, 0, stream>>>(
        y, DIMC, w1_t, DIMC, fc1_b, nullptr, 0, hid, HIDC, DIMC, 128, 8);

    // 8) out(fp32) = x2 + hid @ fc2_w + fc2_b  (N=512, K=2048); nM=128 nN=2
    gemm256<1, 1><<<256, 512, 0, stream>>>(
        hid, HIDC, w2_t, HIDC, fc2_b, y, 0, out, DIMC, HIDC, 128, 2);
}

// Round 16
// 632.494 us; speedup vs baseline: 1.1798x; 1.0877x over previous
//
#include <hip/hip_runtime.h>
#include <hip/hip_bf16.h>
#include <math.h>
#include <stdint.h>

// ---------------------------------------------------------------------------
// SwinTransformerBlock1D.  Inputs fp32, output fp32, internal bf16 MFMA.
// B=4 L=8192 DIM=512 HEADS=8 WIN=256 HEAD_DIM=64 HID=2048.
// R21 = R18/R20 unchanged resubmit.  R20 measured 688us with counters
//     byte-identical to R18's 634us run (FETCH/WRITE/VGPR/LDS/occupancy all
//     equal; dur and hbm_gbps both scaled 1.37x) => container clock
//     throttle, not a kernel effect.  No change; re-roll the node.
// Content: R13 gemm256 (4-phase 2-tile counted-vmcnt pipeline, swapped-
//     operand MFMA + vectorized epilogue, XCD swizzle) + R18 attention
//     (swapped QK^T, one q-row/lane softmax, Q global->reg, 38.2KB LDS,
//     P->LDS swizzled overlay, PV vs global Vt, bf16x4 stores).
// MFMA fragment layouts (m89/m91-verified): A[m=lane&15][k=quad*8+j],
// B[n=lane&15][k=quad*8+j]; mfma(X,Y) -> lane(quad,l16) holds
// D[m(X-row)=quad*4+r][n(Y-row)=l16]  (R13-verified swapped mapping).
// ---------------------------------------------------------------------------

typedef __attribute__((ext_vector_type(8))) __bf16 bf16x8;
typedef __attribute__((ext_vector_type(4))) __bf16 bf16x4;
typedef __attribute__((ext_vector_type(4))) float  f32x4;

#define NTOK  32768
#define DIMC  512
#define HEADS 8
#define WIN   256
#define HD    64
#define HIDC  2048

// async global->LDS, 16B per lane; LDS dest = wave-uniform base + lane*16B
__device__ __forceinline__ void gld16(const __bf16* g, __bf16* l)
{
    __builtin_amdgcn_global_load_lds(
        (const __attribute__((address_space(1))) void*)g,
        (__attribute__((address_space(3))) void*)l, 16, 0, 0);
}

// asm ds_read_b128 at base VGPR address + literal byte offset.
#define DSR(dst, base, off) \
    asm volatile("ds_read_b128 %0, %1 offset:" off : "=v"(dst) : "v"(base))

// ---------------- 256x256 GEMM, 4-phase, 2-tile-deep pipeline (R13) --------
template<int MODE, int OUTF>
__global__ __launch_bounds__(512, 2) void gemm256(
    const __bf16* __restrict__ A, int lda,
    const __bf16* __restrict__ Bt, int ldb,
    const float* __restrict__ bias,
    const void* __restrict__ res, int res_f32,
    void* __restrict__ C, int ldc, int K,
    int nM, int nN)
{
    __shared__ __bf16 lds[2][2][16384];   // [buf][A=0/B=1][slice*512 + lane*8]
    const int tid  = threadIdx.x;
    const int wave = tid >> 6, lane = tid & 63;
    const int quad = lane >> 4, l16 = lane & 15;
    const int wm = wave >> 2, wn = wave & 3;   // 2x4 wave grid

    // XCD swizzle: id%8 = XCD; each XCD owns nM/8 consecutive m-tiles.
    const int id  = blockIdx.x;
    const int xcd = id & 7;
    const int lid = id >> 3;
    const int mq  = lid / nN;
    const int mt  = xcd * (nM >> 3) + mq;
    const int nt  = lid - mq * nN;
    const int m0 = mt * 256, n0 = nt * 256;

    int aoff[4], boff[4];
    #pragma unroll
    for (int j = 0; j < 4; j++) {
        const int S = wave * 4 + j;
        const int row = (S >> 1) * 16 + l16;
        const int kof = (S & 1) * 32 + quad * 8;
        aoff[j] = (m0 + row) * lda + kof;
        boff[j] = (n0 + row) * ldb + kof;
    }

    const uint32_t lds0 =
        (uint32_t)(uintptr_t)(__attribute__((address_space(3))) void*)&lds[0][0][0];
    const uint32_t aAd0 = lds0 + wm * 16384 + lane * 16;
    const uint32_t bAd0 = lds0 + 32768 + wn * 8192 + lane * 16;

    f32x4 acc[8][4] = {};
    bf16x8 rA[4][2], rB[4][2];

    const int ntk = K >> 6;

    #pragma unroll
    for (int j = 0; j < 4; j++) {
        gld16(A  + aoff[j], &lds[0][0][(wave * 4 + j) * 512]);
        gld16(Bt + boff[j], &lds[0][1][(wave * 4 + j) * 512]);
    }
    #pragma unroll
    for (int j = 0; j < 4; j++) {
        gld16(A  + aoff[j] + 64, &lds[1][0][(wave * 4 + j) * 512]);
        gld16(Bt + boff[j] + 64, &lds[1][1][(wave * 4 + j) * 512]);
    }
    asm volatile("s_waitcnt vmcnt(8)");
    __builtin_amdgcn_s_barrier();

    for (int t = 0; t < ntk; ++t) {
        const int buf = t & 1;
        const uint32_t aAd = aAd0 + buf * 65536;
        const uint32_t bAd = bAd0 + buf * 65536;
        const bool pf = (t + 2 < ntk);
        const int kn = (t + 2) << 6;

        // ---- phase 0: ds_read A m0-3 + B n0-1; mfma m0-3 x n0-1
        DSR(rA[0][0], aAd, "0");    DSR(rA[0][1], aAd, "1024");
        DSR(rA[1][0], aAd, "2048"); DSR(rA[1][1], aAd, "3072");
        DSR(rA[2][0], aAd, "4096"); DSR(rA[2][1], aAd, "5120");
        DSR(rA[3][0], aAd, "6144"); DSR(rA[3][1], aAd, "7168");
        DSR(rB[0][0], bAd, "0");    DSR(rB[0][1], bAd, "1024");
        DSR(rB[1][0], bAd, "2048"); DSR(rB[1][1], bAd, "3072");
        __builtin_amdgcn_s_barrier();
        asm volatile("s_waitcnt lgkmcnt(0)");
        __builtin_amdgcn_sched_barrier(0);
        __builtin_amdgcn_s_setprio(1);
        #pragma unroll
        for (int i = 0; i < 4; i++)
            #pragma unroll
            for (int j = 0; j < 2; j++)
                #pragma unroll
                for (int ks = 0; ks < 2; ks++)
                    acc[i][j] = __builtin_amdgcn_mfma_f32_16x16x32_bf16(
                        rB[j][ks], rA[i][ks], acc[i][j], 0, 0, 0);
        __builtin_amdgcn_s_setprio(0);
        __builtin_amdgcn_s_barrier();

        // ---- phase 1: ds_read B n2-3; mfma m0-3 x n2-3
        DSR(rB[2][0], bAd, "4096"); DSR(rB[2][1], bAd, "5120");
        DSR(rB[3][0], bAd, "6144"); DSR(rB[3][1], bAd, "7168");
        __builtin_amdgcn_s_barrier();
        asm volatile("s_waitcnt lgkmcnt(0)");
        __builtin_amdgcn_sched_barrier(0);
        __builtin_amdgcn_s_setprio(1);
        #pragma unroll
        for (int i = 0; i < 4; i++)
            #pragma unroll
            for (int j = 2; j < 4; j++)
                #pragma unroll
                for (int ks = 0; ks < 2; ks++)
                    acc[i][j] = __builtin_amdgcn_mfma_f32_16x16x32_bf16(
                        rB[j][ks], rA[i][ks], acc[i][j], 0, 0, 0);
        __builtin_amdgcn_s_setprio(0);
        __builtin_amdgcn_s_barrier();

        // ---- phase 2: ds_read A m4-7; stage B(t+2)
        DSR(rA[0][0], aAd, "8192");  DSR(rA[0][1], aAd, "9216");
        DSR(rA[1][0], aAd, "10240"); DSR(rA[1][1], aAd, "11264");
        DSR(rA[2][0], aAd, "12288"); DSR(rA[2][1], aAd, "13312");
        DSR(rA[3][0], aAd, "14336"); DSR(rA[3][1], aAd, "15360");
        if (pf) {
            #pragma unroll
            for (int j = 0; j < 4; j++)
                gld16(Bt + boff[j] + kn, &lds[buf][1][(wave * 4 + j) * 512]);
        }
        __builtin_amdgcn_s_barrier();
        asm volatile("s_waitcnt lgkmcnt(0)");
        __builtin_amdgcn_sched_barrier(0);
        __builtin_amdgcn_s_setprio(1);
        #pragma unroll
        for (int i = 0; i < 4; i++)
            #pragma unroll
            for (int j = 0; j < 2; j++)
                #pragma unroll
                for (int ks = 0; ks < 2; ks++)
                    acc[4 + i][j] = __builtin_amdgcn_mfma_f32_16x16x32_bf16(
                        rB[j][ks], rA[i][ks], acc[4 + i][j], 0, 0, 0);
        __builtin_amdgcn_s_setprio(0);
        __builtin_amdgcn_s_barrier();

        // ---- phase 3: stage A(t+2); mfma m4-7 x n2-3; counted boundary wait
        if (pf) {
            #pragma unroll
            for (int j = 0; j < 4; j++)
                gld16(A + aoff[j] + kn, &lds[buf][0][(wave * 4 + j) * 512]);
        }
        __builtin_amdgcn_s_setprio(1);
        #pragma unroll
        for (int i = 0; i < 4; i++)
            #pragma unroll
            for (int j = 2; j < 4; j++)
                #pragma unroll
                for (int ks = 0; ks < 2; ks++)
                    acc[4 + i][j] = __builtin_amdgcn_mfma_f32_16x16x32_bf16(
                        rB[j][ks], rA[i][ks], acc[4 + i][j], 0, 0, 0);
        __builtin_amdgcn_s_setprio(0);
        if (pf)                  asm volatile("s_waitcnt vmcnt(8)");
        else if (t + 1 < ntk)    asm volatile("s_waitcnt vmcnt(0)");
        __builtin_amdgcn_s_barrier();
    }

    // epilogue (swapped layout): lane(quad,l16) holds, for (i,j),
    // C[m0+wm*128+i*16+l16][n0+wn*64+j*16+quad*4 + r], r=0..3 consecutive.
    #pragma unroll
    for (int i = 0; i < 8; i++) {
        const int row = m0 + wm * 128 + i * 16 + l16;
        #pragma unroll
        for (int j = 0; j < 4; j++) {
            const int colb = n0 + wn * 64 + j * 16 + quad * 4;
            const size_t off = (size_t)row * ldc + colb;
            const f32x4 bv = *(const f32x4*)(bias + colb);
            f32x4 v;
            #pragma unroll
            for (int r = 0; r < 4; r++) v[r] = acc[i][j][r] + bv[r];
            if (MODE == 2) {
                #pragma unroll
                for (int r = 0; r < 4; r++)
                    v[r] = 0.5f * v[r] * (1.0f + erff(v[r] * 0.70710678118654752f));
            }
            if (MODE == 1) {
                if (res_f32) {
                    const f32x4 rv = *(const f32x4*)((const float*)res + off);
                    #pragma unroll
                    for (int r = 0; r < 4; r++) v[r] += rv[r];
                } else {
                    const bf16x4 rv = *(const bf16x4*)((const __bf16*)res + off);
                    #pragma unroll
                    for (int r = 0; r < 4; r++) v[r] += (float)rv[r];
                }
            }
            if (OUTF) {
                *(f32x4*)((float*)C + off) = v;
            } else {
                bf16x4 o;
                #pragma unroll
                for (int r = 0; r < 4; r++) o[r] = (__bf16)v[r];
                *(bf16x4*)((__bf16*)C + off) = o;
            }
        }
    }
}

// ---------------- fused attention: QK^T + bias + softmax + PV (R18) --------
// One block: 64 q-rows x full 256 k for one (window,head).  4 waves.
// QK phase (swapped): mfma(K_frag, Q_frag) -> lane(quad,l16) holds
// S[q = wave*16+l16][k = nb*16+quad*4+r] -- one q-row per lane.  Q loaded
// global->reg (no Qs LDS); K staged in LDS (shared by all waves).
// Softmax: in-lane reduce over 64 vals + shfl_xor(16,32) across quads;
// P-writes 16x b64 per lane into swizzled P overlay on Ks (chunk
// c=nb*2+(quad>>1) at slot c^(row&7), half (quad&1)).  PV phase: wave owns
// rows wave*16+l16 as A-frag m=l16; V^T frags read from global Vt (LLC);
// swapped mfma(vf, pa) -> lane holds out[row=wave*16+l16][d=nb2*16+quad*4+r]
// -> bf16x4 stores.
__global__ __launch_bounds__(256) void attn_fused(
    const __bf16* __restrict__ qkvb, const float* __restrict__ rpb,
    const __bf16* __restrict__ Vt, __bf16* __restrict__ attnO)
{
    __shared__ __align__(16) __bf16 Ks[256 * 72];   // P overlays first 32 KB
    __shared__ float rpbs[320];
    const int bh = blockIdx.y;
    const int bw = bh >> 3, head = bh & 7;
    const int m0 = blockIdx.x * 64;
    const int tid = threadIdx.x;
    const __bf16* qb = qkvb + (size_t)bw * WIN * 1536 + head * HD;

    const int wave = tid >> 6, lane = tid & 63;
    const int quad = lane >> 4, l16 = lane & 15;

    // Q direct global->reg: wave's q-row = m0 + wave*16 + l16 (B-operand).
    bf16x8 af[2];
    #pragma unroll
    for (int ks = 0; ks < 2; ks++)
        af[ks] = *(const bf16x8*)(qb + (size_t)(m0 + wave * 16 + l16) * 1536
                                  + ks * 32 + quad * 8);

    {   // stage K (256x64), rows of 64 elems = 8 x bf16x8; and rpb slice
        const int row = tid >> 3, l8 = (tid & 7) * 8;
        #pragma unroll
        for (int p = 0; p < 8; p++) {
            const int r = p * 32 + row;
            *(bf16x8*)(Ks + r * 72 + l8) =
                *(const bf16x8*)(qb + 512 + (size_t)r * 1536 + l8);
        }
        // rpb slice: bias(i,j) = rpb[i-j+255]; i-j+255-m0 in [0,318]
        rpbs[tid] = rpb[(size_t)(m0 + tid) * HEADS + head];
        if (tid < 63) rpbs[256 + tid] = rpb[(size_t)(m0 + 256 + tid) * HEADS + head];
    }
    __syncthreads();

    // QK^T swapped: acc[nb][r] = S[q][k=nb*16+quad*4+r], q = wave*16+l16
    f32x4 acc[16];
    #pragma unroll
    for (int nb = 0; nb < 16; nb++) acc[nb] = (f32x4){0.f, 0.f, 0.f, 0.f};
    #pragma unroll
    for (int nb = 0; nb < 16; nb++) {
        #pragma unroll
        for (int ks = 0; ks < 2; ks++) {
            bf16x8 bf = *(const bf16x8*)(Ks + (nb * 16 + l16) * 72 + ks * 32 + quad * 8);
            acc[nb] = __builtin_amdgcn_mfma_f32_16x16x32_bf16(bf, af[ks], acc[nb], 0, 0, 0);
        }
    }
    // scale + bias: q = wave*16+l16 (local), k = nb*16+quad*4+r
    const int ql = wave * 16 + l16;
    #pragma unroll
    for (int nb = 0; nb < 16; nb++)
        #pragma unroll
        for (int r = 0; r < 4; r++)
            acc[nb][r] = acc[nb][r] * 0.125f
                       + rpbs[ql - (nb * 16 + quad * 4 + r) + 255];

    __syncthreads();   // all K-reads done; safe to overlay P on Ks

    // softmax for row ql (one row per lane): in-lane + cross-quad shuffles
    char* Pb = (char*)Ks;
    {
        float m = -1e30f;
        #pragma unroll
        for (int nb = 0; nb < 16; nb++)
            #pragma unroll
            for (int r = 0; r < 4; r++) m = fmaxf(m, acc[nb][r]);
        m = fmaxf(m, __shfl_xor(m, 16));
        m = fmaxf(m, __shfl_xor(m, 32));
        float s = 0.f;
        #pragma unroll
        for (int nb = 0; nb < 16; nb++)
            #pragma unroll
            for (int r = 0; r < 4; r++) {
                acc[nb][r] = __expf(acc[nb][r] - m);
                s += acc[nb][r];
            }
        s += __shfl_xor(s, 16);
        s += __shfl_xor(s, 32);
        const float inv = 1.0f / s;
        // P-write: b64 per nb at row ql, cols nb*16+quad*4..+3
        const int rx = ql & 7;
        #pragma unroll
        for (int nb = 0; nb < 16; nb++) {
            bf16x4 o;
            #pragma unroll
            for (int r = 0; r < 4; r++) o[r] = (__bf16)(acc[nb][r] * inv);
            const int c = nb * 2 + (quad >> 1);           // 16B content chunk
            *(bf16x4*)(Pb + ql * 512 + ((c ^ rx) << 4) + ((quad & 1) << 3)) = o;
        }
    }
    __syncthreads();   // P complete

    // PV: wave computes rows wave*16+l16 (A-frag m=l16), all 64 d.
    const __bf16* Vtb = Vt + (size_t)bh * (HD * WIN);
    const int prow = wave * 16 + l16;
    const int px = prow & 7;                               // == l16 & 7
    f32x4 acc2[4] = {};
    #pragma unroll
    for (int ks2 = 0; ks2 < 8; ks2++) {
        const bf16x8 pa = *(const bf16x8*)(Pb + prow * 512
                                + (((ks2 * 4 + quad) ^ px) << 4));
        #pragma unroll
        for (int nb2 = 0; nb2 < 4; nb2++) {
            const bf16x8 vf = *(const bf16x8*)(Vtb + (size_t)(nb2 * 16 + l16) * WIN
                                + ks2 * 32 + quad * 8);
            acc2[nb2] = __builtin_amdgcn_mfma_f32_16x16x32_bf16(vf, pa, acc2[nb2], 0, 0, 0);
        }
    }
    // store: out[row=m0+wave*16+l16][d=head*64+nb2*16+quad*4 + r]
    {
        const int i = m0 + wave * 16 + l16;
        __bf16* ob = attnO + (size_t)(bw * WIN + i) * DIMC + head * HD;
        #pragma unroll
        for (int nb2 = 0; nb2 < 4; nb2++) {
            bf16x4 o;
            #pragma unroll
            for (int r = 0; r < 4; r++) o[r] = (__bf16)acc2[nb2][r];
            *(bf16x4*)(ob + nb2 * 16 + quad * 4) = o;
        }
    }
}

// ---------------- V^T per (window,head): Vt[d][j] = V[j][d] ----------------
__global__ __launch_bounds__(256) void vtrans(
    const __bf16* __restrict__ qkvb, __bf16* __restrict__ Vt, int bh_base)
{
    __shared__ __align__(16) __bf16 s[WIN * 72];
    const int bh = bh_base + blockIdx.x;
    const int bw = bh >> 3, head = bh & 7;
    const int tid = threadIdx.x;
    const __bf16* V = qkvb + (size_t)bw * WIN * 1536 + 1024 + head * HD;
    #pragma unroll
    for (int it = 0; it < 8; it++) {
        int idx = it * 256 + tid;
        int j = idx >> 3;
        int d0 = (idx & 7) * 8;
        *(bf16x8*)(s + j * 72 + d0) = *(const bf16x8*)(V + (size_t)j * 1536 + d0);
    }
    __syncthreads();
    __bf16* out = Vt + (size_t)blockIdx.x * (HD * WIN);
    #pragma unroll
    for (int it = 0; it < 8; it++) {
        int idx = it * 256 + tid;
        int d  = idx >> 5;
        int j0 = (idx & 31) * 8;
        bf16x8 v;
        #pragma unroll
        for (int j = 0; j < 8; j++) v[j] = s[(j0 + j) * 72 + d];
        *(bf16x8*)(out + (size_t)d * WIN + j0) = v;
    }
}

// ---------------- LayerNorm: one wave per token ----------------------------
__global__ __launch_bounds__(256) void ln_kernel(
    const void* X, int xf,
    const float* __restrict__ g, const float* __restrict__ b,
    __bf16* O)
{
    const int tok  = blockIdx.x * 4 + (threadIdx.x >> 6);
    const int lane = threadIdx.x & 63;
    const size_t base = (size_t)tok * DIMC + lane * 8;
    float v[8];
    if (xf) {
        const float* xp = (const float*)X + base;
        f32x4 a = *(const f32x4*)xp;
        f32x4 c = *(const f32x4*)(xp + 4);
        #pragma unroll
        for (int j = 0; j < 4; j++) { v[j] = a[j]; v[4 + j] = c[j]; }
    } else {
        bf16x8 xv = *(const bf16x8*)((const __bf16*)X + base);
        #pragma unroll
        for (int j = 0; j < 8; j++) v[j] = (float)xv[j];
    }
    float s = 0.f, s2 = 0.f;
    #pragma unroll
    for (int j = 0; j < 8; j++) { s += v[j]; s2 += v[j] * v[j]; }
    #pragma unroll
    for (int off = 32; off; off >>= 1) { s += __shfl_xor(s, off); s2 += __shfl_xor(s2, off); }
    const float mean = s * (1.0f / DIMC);
    const float var  = s2 * (1.0f / DIMC) - mean * mean;
    const float rstd = rsqrtf(var + 1e-5f);
    f32x4 ga = *(const f32x4*)(g + lane * 8);
    f32x4 gc = *(const f32x4*)(g + lane * 8 + 4);
    f32x4 ba = *(const f32x4*)(b + lane * 8);
    f32x4 bc = *(const f32x4*)(b + lane * 8 + 4);
    bf16x8 ov;
    #pragma unroll
    for (int j = 0; j < 4; j++) {
        ov[j]     = (__bf16)((v[j]     - mean) * rstd * ga[j] + ba[j]);
        ov[4 + j] = (__bf16)((v[4 + j] - mean) * rstd * gc[j] + bc[j]);
    }
    *(bf16x8*)(O + base) = ov;
}

// ---------------- weight transpose+cast: fp32 KxN -> bf16 NxK --------------
__global__ __launch_bounds__(256) void wtrans(
    const float* __restrict__ W, __bf16* __restrict__ Wt, int K, int N)
{
    __shared__ __align__(16) __bf16 s[64 * 72];
    const int kb = blockIdx.y * 64, nb = blockIdx.x * 64;
    const int tid = threadIdx.x;
    #pragma unroll
    for (int it = 0; it < 2; it++) {
        int idx = it * 256 + tid;
        int lk = idx >> 3;
        int ln = (idx & 7) * 8;
        const float* wp = W + (size_t)(kb + lk) * N + nb + ln;
        f32x4 a = *(const f32x4*)wp;
        f32x4 c = *(const f32x4*)(wp + 4);
        bf16x8 v;
        #pragma unroll
        for (int j = 0; j < 4; j++) { v[j] = (__bf16)a[j]; v[4 + j] = (__bf16)c[j]; }
        *(bf16x8*)(s + lk * 72 + ln) = v;
    }
    __syncthreads();
    #pragma unroll
    for (int it = 0; it < 2; it++) {
        int idx = it * 256 + tid;
        int ln  = idx >> 3;
        int lkv = (idx & 7) * 8;
        bf16x8 v;
        #pragma unroll
        for (int j = 0; j < 8; j++) v[j] = s[(lkv + j) * 72 + ln];
        *(bf16x8*)(Wt + (size_t)(nb + ln) * K + kb + lkv) = v;
    }
}

// ---------------------------------------------------------------------------
extern "C" void kernel_launch(void* const* d_in, const int* in_sizes, int n_in,
                              void* d_out, int out_size, void* d_ws, size_t ws_size,
                              hipStream_t stream)
{
    const float* x      = (const float*)d_in[0];
    const float* n1g    = (const float*)d_in[1];
    const float* n1b    = (const float*)d_in[2];
    const float* qkv_w  = (const float*)d_in[3];
    const float* qkv_b  = (const float*)d_in[4];
    const float* rpb    = (const float*)d_in[5];
    const float* proj_w = (const float*)d_in[6];
    const float* proj_b = (const float*)d_in[7];
    const float* n2g    = (const float*)d_in[8];
    const float* n2b    = (const float*)d_in[9];
    const float* fc1_w  = (const float*)d_in[10];
    const float* fc1_b  = (const float*)d_in[11];
    const float* fc2_w  = (const float*)d_in[12];
    const float* fc2_b  = (const float*)d_in[13];
    float* out = (float*)d_out;

    // workspace layout (bytes); slots reused sequentially
    char* ws = (char*)d_ws;
    __bf16* qkvb  = (__bf16*)(ws + 0);           // 96 MB (dead after attn)
    __bf16* hid   = (__bf16*)(ws + 0);           // 128 MB (steps 7-8)
    __bf16* Vt    = (__bf16*)(ws + 100663296);   // 96..128 MB (dead after attn)
    __bf16* h     = (__bf16*)(ws + 134217728);   // LN1 out; later y/x2
    __bf16* y     = h;
    __bf16* attnO = (__bf16*)(ws + 167772160);
    __bf16* wq_t  = (__bf16*)(ws + 209715200);   // 1536x512
    __bf16* wp_t  = (__bf16*)(ws + 211288064);   // 512x512
    __bf16* w1_t  = (__bf16*)(ws + 211812352);   // 2048x512
    __bf16* w2_t  = (__bf16*)(ws + 213909504);   // 512x2048

    // 1) weight transposes (tiny)
    wtrans<<<dim3(1536 / 64, 512 / 64),  256, 0, stream>>>(qkv_w, wq_t, 512, 1536);
    wtrans<<<dim3(512 / 64,  512 / 64),  256, 0, stream>>>(proj_w, wp_t, 512, 512);
    wtrans<<<dim3(2048 / 64, 512 / 64),  256, 0, stream>>>(fc1_w, w1_t, 512, 2048);
    wtrans<<<dim3(512 / 64,  2048 / 64), 256, 0, stream>>>(fc2_w, w2_t, 2048, 512);

    // 2) LN1: h = LN(x)
    ln_kernel<<<NTOK / 4, 256, 0, stream>>>(x, 1, n1g, n1b, h);

    // 3) qkv = h @ qkv_w + qkv_b   (M=32768, N=1536, K=512); nM=128 nN=6
    gemm256<0, 0><<<768, 512, 0, stream>>>(
        h, DIMC, wq_t, DIMC, qkv_b, nullptr, 0, qkvb, 1536, DIMC, 128, 6);

    // 4) attention: V^T then fused QK^T+softmax+PV over all 1024 (bw,head)
    vtrans<<<1024, 256, 0, stream>>>(qkvb, Vt, 0);
    attn_fused<<<dim3(4, 1024), 256, 0, stream>>>(qkvb, rpb, Vt, attnO);

    // 5) y = x + attnO @ proj_w + proj_b   (N=512, K=512); nM=128 nN=2
    gemm256<1, 0><<<256, 512, 0, stream>>>(
        attnO, DIMC, wp_t, DIMC, proj_b, x, 1, y, DIMC, DIMC, 128, 2);

    // 6) LN2 in place: x2 = LN(y)
    ln_kernel<<<NTOK / 4, 256, 0, stream>>>(y, 0, n2g, n2b, y);

    // 7) hid = gelu(x2 @ fc1_w + fc1_b)   (N=2048, K=512); nM=128 nN=8
    gemm256<2, 0><<<1024, 512, 0, stream>>>(
        y, DIMC, w1_t, DIMC, fc1_b, nullptr, 0, hid, HIDC, DIMC, 128, 8);

    // 8) out(fp32) = x2 + hid @ fc2_w + fc2_b  (N=512, K=2048); nM=128 nN=2
    gemm256<1, 1><<<256, 512, 0, stream>>>(
        hid, HIDC, w2_t, HIDC, fc2_b, y, 0, out, DIMC, HIDC, 128, 2);
}